// Round 8
// baseline (3010.978 us; speedup 1.0000x reference)
//
#include <hip/hip_runtime.h>

#define T_STEPS 1024
#define FDIM    2048
#define LAT     128
#define HID     256
#define MB      8             // features per block
#define NTHR    256           // 4 waves, 1 per SIMD
#define NBLK    (FDIM / MB)   // 256 blocks = 1/CU

typedef __attribute__((ext_vector_type(8))) short bf16x8;
typedef __attribute__((ext_vector_type(4))) float f32x4;

__device__ __forceinline__ float sigmoidf_(float x) {
    return 1.0f / (1.0f + __expf(-x));
}
__device__ __forceinline__ float tanhf_(float x) {
    float ax = fabsf(x);
    float e  = __expf(-2.0f * ax);
    float t  = (1.0f - e) / (1.0f + e);
    return copysignf(t, x);
}
__device__ __forceinline__ unsigned short f2bu(float x) {   // fp32->bf16 RNE bits
    unsigned u = __float_as_uint(x);
    u += 0x7fffu + ((u >> 16) & 1u);
    return (unsigned short)(u >> 16);
}
__device__ __forceinline__ short f2b(float x) { return (short)f2bu(x); }
__device__ __forceinline__ unsigned pk2(float a, float b) { // packed bf16x2 RNE
    return (unsigned)f2bu(a) | ((unsigned)f2bu(b) << 16);
}

// Activation^T LDS layout (fragB): element (k, m) at short-offset
//   (k>>3)*64 + m*8 + (k&7)     [m in 0..7]
// B-frag read for lane (col,qd): 16B contiguous at (kb*4+qd)*64 + (col&7)*8.
// cols 8..15 duplicate cols 0..7 (same-address broadcast = free).

__global__ __launch_bounds__(NTHR, 1)
void odernn_kernel(const float* __restrict__ times,
                   const float* __restrict__ vals,
                   const float* __restrict__ mask,
                   const float* __restrict__ W1,  const float* __restrict__ b1,
                   const float* __restrict__ W2,  const float* __restrict__ b2,
                   const float* __restrict__ W_ih, const float* __restrict__ b_ih,
                   const float* __restrict__ Whh, const float* __restrict__ b_hh,
                   float* __restrict__ out)
{
    __shared__ float dts_s[T_STEPS];   // 4 KB
    __shared__ short hTpre[16 * 64];   // 2 KB  bf16 h^T (post-GRU), read by p1
    __shared__ short hTpost[16 * 64];  // 2 KB  bf16 h^T (post-ODE), read by p3
    __shared__ short uT[32 * 64];      // 4 KB  bf16 u^T
    // total ~12 KB

    const int tid = threadIdx.x;
    const int w   = tid >> 6;          // wave 0..3
    const int ln  = tid & 63;
    const int col = ln & 15;           // C/D col = feature m (valid < 8)
    const int qd  = ln >> 4;           // quad; C/D row = qd*4 + reg
    const int m8  = ln & 7;            // dup-col feature index
    const bool valid = (col < 8);
    const int fbase = blockIdx.x * MB;
    const int rbase = qd * 64 + m8 * 8;     // B-frag read offset base (shorts)

    // ---------- prologue ----------
    for (int e = tid; e < T_STEPS; e += NTHR)
        dts_s[e] = (e == 0) ? 0.0f : (times[T_STEPS - e] - times[T_STEPS - 1 - e]);
    for (int e = tid; e < 16 * 64; e += NTHR) { hTpre[e] = 0; hTpost[e] = 0; }
    for (int e = tid; e < 32 * 64; e += NTHR) uT[e] = 0;

    // A-operand weight fragment: lane holds W[tb+col][kb*32 + qd*8 + j]
    auto loadW = [&](const float* __restrict__ W, int K, int tb, int kb) -> bf16x8 {
        const float* p = W + (size_t)(tb + col) * K + kb * 32 + qd * 8;
        const float4 a = *(const float4*)p;
        const float4 b = *(const float4*)(p + 4);
        bf16x8 r;
        r[0] = f2b(a.x); r[1] = f2b(a.y); r[2] = f2b(a.z); r[3] = f2b(a.w);
        r[4] = f2b(b.x); r[5] = f2b(b.y); r[6] = f2b(b.z); r[7] = f2b(b.w);
        return r;
    };

    // weights: expected to land in AGPRs (MFMA A-operand legal from AGPR)
    bf16x8 w1a[4][4];               // p1: u-tiles {4w..4w+3}, K=128
    #pragma unroll
    for (int i = 0; i < 4; ++i)
        #pragma unroll
        for (int kb = 0; kb < 4; ++kb) w1a[i][kb] = loadW(W1, LAT, (4 * w + i) * 16, kb);
    bf16x8 w2a[2][8];               // p2: ode-tiles {2w,2w+1}, K=256
    #pragma unroll
    for (int i = 0; i < 2; ++i)
        #pragma unroll
        for (int kb = 0; kb < 8; ++kb) w2a[i][kb] = loadW(W2, HID, (2 * w + i) * 16, kb);
    bf16x8 wha[3][2][4];            // p3: per gate g, tiles {2w,2w+1}, K=128
    #pragma unroll
    for (int g = 0; g < 3; ++g)
        #pragma unroll
        for (int i = 0; i < 2; ++i)
            #pragma unroll
            for (int kb = 0; kb < 4; ++kb)
                wha[g][i][kb] = loadW(Whh, LAT, g * 128 + (2 * w + i) * 16, kb);

    // per-lane bias/row constants (C row = tile*16 + qd*4 + r)
    float b1L[4][4], b2L[2][4], bhL[3][2][4], wihL[3][2][4], bihL[3][2][4];
    #pragma unroll
    for (int i = 0; i < 4; ++i)
        #pragma unroll
        for (int r = 0; r < 4; ++r) b1L[i][r] = b1[(4 * w + i) * 16 + qd * 4 + r];
    #pragma unroll
    for (int i = 0; i < 2; ++i)
        #pragma unroll
        for (int r = 0; r < 4; ++r) {
            const int c = (2 * w + i) * 16 + qd * 4 + r;
            b2L[i][r] = b2[c];
            #pragma unroll
            for (int g = 0; g < 3; ++g) {
                bhL[g][i][r]  = b_hh[g * 128 + c];
                wihL[g][i][r] = W_ih[g * 128 + c];
                bihL[g][i][r] = b_ih[g * 128 + c];
            }
        }
    float hreg[2][4] = {{0.f, 0.f, 0.f, 0.f}, {0.f, 0.f, 0.f, 0.f}};  // fp32 h master

    __syncthreads();

    for (int t = 0; t < T_STEPS; ++t) {
        const float dt = dts_s[t];
        const size_t rowoff = (size_t)(T_STEPS - 1 - t) * FDIM + fbase;
        const float x  = vals[rowoff + m8];       // prefetch; consumed in p3 epi
        const float mk = mask[rowoff + m8];
        const short* p3src;

        if (dt > 0.0f) {
            // ---- p1: u^T = tanh(W1 h^T + b1) ----
            f32x4 a1[4] = {{0,0,0,0},{0,0,0,0},{0,0,0,0},{0,0,0,0}};
            #pragma unroll
            for (int kb = 0; kb < 4; ++kb) {
                const bf16x8 bf = *(const bf16x8*)(hTpre + kb * 256 + rbase);
                #pragma unroll
                for (int i = 0; i < 4; ++i)
                    a1[i] = __builtin_amdgcn_mfma_f32_16x16x32_bf16(w1a[i][kb], bf, a1[i], 0, 0, 0);
            }
            if (valid) {
                #pragma unroll
                for (int i = 0; i < 4; ++i) {
                    const float v0 = tanhf_(a1[i][0] + b1L[i][0]);
                    const float v1 = tanhf_(a1[i][1] + b1L[i][1]);
                    const float v2 = tanhf_(a1[i][2] + b1L[i][2]);
                    const float v3 = tanhf_(a1[i][3] + b1L[i][3]);
                    const int addr = ((4 * w + i) * 2 + (qd >> 1)) * 64 + m8 * 8 + (qd & 1) * 4;
                    uint2 u; u.x = pk2(v0, v1); u.y = pk2(v2, v3);
                    *(uint2*)(uT + addr) = u;
                }
            }
            __syncthreads();

            // ---- p2: ode^T = W2 u^T + b2 ; h += dt*ode (registers) ----
            f32x4 a2[2] = {{0,0,0,0},{0,0,0,0}};
            #pragma unroll
            for (int kb = 0; kb < 8; ++kb) {
                const bf16x8 bf = *(const bf16x8*)(uT + kb * 256 + rbase);
                #pragma unroll
                for (int i = 0; i < 2; ++i)
                    a2[i] = __builtin_amdgcn_mfma_f32_16x16x32_bf16(w2a[i][kb], bf, a2[i], 0, 0, 0);
            }
            #pragma unroll
            for (int i = 0; i < 2; ++i) {
                #pragma unroll
                for (int r = 0; r < 4; ++r)
                    hreg[i][r] = fmaf(dt, a2[i][r] + b2L[i][r], hreg[i][r]);
                if (valid) {
                    const int addr = ((2 * w + i) * 2 + (qd >> 1)) * 64 + m8 * 8 + (qd & 1) * 4;
                    uint2 u; u.x = pk2(hreg[i][0], hreg[i][1]); u.y = pk2(hreg[i][2], hreg[i][3]);
                    *(uint2*)(hTpost + addr) = u;
                }
            }
            __syncthreads();
            p3src = hTpost;
        } else {
            p3src = hTpre;
        }

        // ---- p3: gh^T = Whh h'^T + b_hh, then full GRU in-register ----
        f32x4 a3[3][2] = {{{0,0,0,0},{0,0,0,0}},{{0,0,0,0},{0,0,0,0}},{{0,0,0,0},{0,0,0,0}}};
        #pragma unroll
        for (int kb = 0; kb < 4; ++kb) {
            const bf16x8 bf = *(const bf16x8*)(p3src + kb * 256 + rbase);
            #pragma unroll
            for (int g = 0; g < 3; ++g)
                #pragma unroll
                for (int i = 0; i < 2; ++i)
                    a3[g][i] = __builtin_amdgcn_mfma_f32_16x16x32_bf16(wha[g][i][kb], bf, a3[g][i], 0, 0, 0);
        }
        if (!(dt > 0.0f)) __syncthreads();   // rare path: protect hTpre reads before overwrite

        #pragma unroll
        for (int i = 0; i < 2; ++i) {
            float hn[4];
            #pragma unroll
            for (int r = 0; r < 4; ++r) {
                const float gR = a3[0][i][r] + bhL[0][i][r];
                const float gZ = a3[1][i][r] + bhL[1][i][r];
                const float gN = a3[2][i][r] + bhL[2][i][r];
                const float rr = sigmoidf_(fmaf(x, wihL[0][i][r], bihL[0][i][r]) + gR);
                const float zz = sigmoidf_(fmaf(x, wihL[1][i][r], bihL[1][i][r]) + gZ);
                const float nn = tanhf_(fmaf(rr, gN, fmaf(x, wihL[2][i][r], bihL[2][i][r])));
                const float hv = hreg[i][r];
                const float hc = (1.0f - zz) * nn + zz * hv;
                hn[r] = mk * hc + (1.0f - mk) * hv;
                hreg[i][r] = hn[r];
            }
            if (valid) {
                const int addr = ((2 * w + i) * 2 + (qd >> 1)) * 64 + m8 * 8 + (qd & 1) * 4;
                uint2 u; u.x = pk2(hn[0], hn[1]); u.y = pk2(hn[2], hn[3]);
                *(uint2*)(hTpre + addr) = u;
            }
        }
        __syncthreads();
    }

    if (valid) {
        #pragma unroll
        for (int i = 0; i < 2; ++i) {
            float4 o = make_float4(hreg[i][0], hreg[i][1], hreg[i][2], hreg[i][3]);
            *(float4*)(out + (size_t)(fbase + m8) * LAT + (2 * w + i) * 16 + qd * 4) = o;
        }
    }
}

extern "C" void kernel_launch(void* const* d_in, const int* in_sizes, int n_in,
                              void* d_out, int out_size, void* d_ws, size_t ws_size,
                              hipStream_t stream) {
    const float* times = (const float*)d_in[0];
    const float* vals  = (const float*)d_in[1];
    const float* mask  = (const float*)d_in[2];
    const float* W1    = (const float*)d_in[3];
    const float* b1    = (const float*)d_in[4];
    const float* W2    = (const float*)d_in[5];
    const float* b2    = (const float*)d_in[6];
    const float* W_ih  = (const float*)d_in[7];
    const float* b_ih  = (const float*)d_in[8];
    const float* Whh   = (const float*)d_in[9];
    const float* b_hh  = (const float*)d_in[10];
    float* out = (float*)d_out;

    odernn_kernel<<<NBLK, NTHR, 0, stream>>>(times, vals, mask,
                                             W1, b1, W2, b2,
                                             W_ih, b_ih, Whh, b_hh, out);
}

// Round 9
// 1661.424 us; speedup vs baseline: 1.8123x; 1.8123x over previous
//
#include <hip/hip_runtime.h>

#define T_STEPS 1024
#define FDIM    2048
#define LAT     128
#define HID     256
#define MB      8             // features per block
#define NTHR    512           // 8 waves, 2 per SIMD
#define NBLK    (FDIM / MB)   // 256 blocks = 1/CU

typedef __attribute__((ext_vector_type(8))) short bf16x8;
typedef __attribute__((ext_vector_type(4))) float f32x4;

// NO divisions: -O3 without -ffast-math expands '/' to ~12-instr precise
// div sequences (R7: 40 divs/lane/step ~= half the VALU time). v_rcp_f32
// is ~1 ULP, absmax threshold is 2% relative -> rcp is more than enough.
__device__ __forceinline__ float sigmoidf_(float x) {
    return __builtin_amdgcn_rcpf(1.0f + __expf(-x));
}
__device__ __forceinline__ float tanhf_(float x) {
    float ax = fabsf(x);
    float e  = __expf(-2.0f * ax);
    float t  = (1.0f - e) * __builtin_amdgcn_rcpf(1.0f + e);
    return copysignf(t, x);
}
__device__ __forceinline__ unsigned short f2bu(float x) {   // fp32->bf16 RNE bits
    unsigned u = __float_as_uint(x);
    u += 0x7fffu + ((u >> 16) & 1u);
    return (unsigned short)(u >> 16);
}
__device__ __forceinline__ short f2b(float x) { return (short)f2bu(x); }
__device__ __forceinline__ unsigned pk2(float a, float b) { // packed bf16x2 RNE
    return (unsigned)f2bu(a) | ((unsigned)f2bu(b) << 16);
}

// Activation^T LDS layout (B-operand): element (k, m) at short-offset
//   (k>>3)*64 + m*8 + (k&7)   [m in 0..7]
// B-frag read for lane (col,qd): 16B contiguous at (kb*4+qd)*64 + (col&7)*8;
// cols 8..15 duplicate cols 0..7 (same-address broadcast).

__global__ __launch_bounds__(NTHR, 2)
void odernn_kernel(const float* __restrict__ times,
                   const float* __restrict__ vals,
                   const float* __restrict__ mask,
                   const float* __restrict__ W1,  const float* __restrict__ b1,
                   const float* __restrict__ W2,  const float* __restrict__ b2,
                   const float* __restrict__ W_ih, const float* __restrict__ b_ih,
                   const float* __restrict__ Whh, const float* __restrict__ b_hh,
                   float* __restrict__ out)
{
    __shared__ float dts_s[T_STEPS];   // 4 KB
    __shared__ short hTpre[16 * 64];   // 2 KB  bf16 h^T (post-GRU), read by p1 & dt==0 p3
    __shared__ short hTpost[16 * 64];  // 2 KB  bf16 h^T (post-ODE), read by p3
    __shared__ short uT[32 * 64];      // 4 KB  bf16 u^T
    // total ~12 KB

    const int tid = threadIdx.x;
    const int w   = tid >> 6;          // wave 0..7
    const int ln  = tid & 63;
    const int col = ln & 15;           // C/D col = feature m (valid < 8)
    const int qd  = ln >> 4;           // quad; C/D row = qd*4 + reg
    const int m8  = ln & 7;            // dup-col feature index
    const bool valid = (col < 8);
    const int fbase = blockIdx.x * MB;
    const int rbase = qd * 64 + m8 * 8;     // B-frag read offset (shorts)

    // ---------- prologue ----------
    for (int e = tid; e < T_STEPS; e += NTHR)
        dts_s[e] = (e == 0) ? 0.0f : (times[T_STEPS - e] - times[T_STEPS - 1 - e]);
    for (int e = tid; e < 16 * 64; e += NTHR) { hTpre[e] = 0; hTpost[e] = 0; }
    for (int e = tid; e < 32 * 64; e += NTHR) uT[e] = 0;

    // A-operand weight fragment: lane holds W[tb+col][kb*32 + qd*8 + j]
    auto loadW = [&](const float* __restrict__ W, int K, int tb, int kb) -> bf16x8 {
        const float* p = W + (size_t)(tb + col) * K + kb * 32 + qd * 8;
        const float4 a = *(const float4*)p;
        const float4 b = *(const float4*)(p + 4);
        bf16x8 r;
        r[0] = f2b(a.x); r[1] = f2b(a.y); r[2] = f2b(a.z); r[3] = f2b(a.w);
        r[4] = f2b(b.x); r[5] = f2b(b.y); r[6] = f2b(b.z); r[7] = f2b(b.w);
        return r;
    };

    // per-wave tile ownership (112 weight regs/lane, AGPR-resident):
    // p1: u-tiles {2w, 2w+1}; p2: ode-tile w; p3: gate tiles {w, 8+w, 16+w}
    bf16x8 w1a[2][4];
    #pragma unroll
    for (int i = 0; i < 2; ++i)
        #pragma unroll
        for (int kb = 0; kb < 4; ++kb) w1a[i][kb] = loadW(W1, LAT, (2 * w + i) * 16, kb);
    bf16x8 w2a[8];
    #pragma unroll
    for (int kb = 0; kb < 8; ++kb) w2a[kb] = loadW(W2, HID, w * 16, kb);
    bf16x8 wha[3][4];
    #pragma unroll
    for (int g = 0; g < 3; ++g)
        #pragma unroll
        for (int kb = 0; kb < 4; ++kb)
            wha[g][kb] = loadW(Whh, LAT, g * 128 + w * 16, kb);

    // per-lane constants (C row of own latent tile = w*16 + qd*4 + r)
    float b1L[2][4], b2L[4], bhL[3][4], wihL[3][4], bihL[3][4];
    #pragma unroll
    for (int i = 0; i < 2; ++i)
        #pragma unroll
        for (int r = 0; r < 4; ++r) b1L[i][r] = b1[(2 * w + i) * 16 + qd * 4 + r];
    #pragma unroll
    for (int r = 0; r < 4; ++r) {
        const int c = w * 16 + qd * 4 + r;
        b2L[r] = b2[c];
        #pragma unroll
        for (int g = 0; g < 3; ++g) {
            bhL[g][r]  = b_hh[g * 128 + c];
            wihL[g][r] = W_ih[g * 128 + c];
            bihL[g][r] = b_ih[g * 128 + c];
        }
    }
    float hreg[4] = {0.f, 0.f, 0.f, 0.f};   // fp32 master h, rows w*16+qd*4+r, feature m8
    const int myAddr = (w * 2 + (qd >> 1)) * 64 + m8 * 8 + (qd & 1) * 4;  // own-tile store

    __syncthreads();

    for (int t = 0; t < T_STEPS; ++t) {
        const float dt = dts_s[t];
        const size_t rowoff = (size_t)(T_STEPS - 1 - t) * FDIM + fbase;
        const float x  = vals[rowoff + m8];       // prefetch; used in p3 epilogue
        const float mk = mask[rowoff + m8];
        const short* p3src;

        if (dt > 0.0f) {
            // ---- p1: u^T = tanh(W1 h^T + b1), 2 tiles ----
            f32x4 a1[2] = {{0,0,0,0},{0,0,0,0}};
            #pragma unroll
            for (int kb = 0; kb < 4; ++kb) {
                const bf16x8 bf = *(const bf16x8*)(hTpre + kb * 256 + rbase);
                #pragma unroll
                for (int i = 0; i < 2; ++i)
                    a1[i] = __builtin_amdgcn_mfma_f32_16x16x32_bf16(w1a[i][kb], bf, a1[i], 0, 0, 0);
            }
            if (valid) {
                #pragma unroll
                for (int i = 0; i < 2; ++i) {
                    const float v0 = tanhf_(a1[i][0] + b1L[i][0]);
                    const float v1 = tanhf_(a1[i][1] + b1L[i][1]);
                    const float v2 = tanhf_(a1[i][2] + b1L[i][2]);
                    const float v3 = tanhf_(a1[i][3] + b1L[i][3]);
                    const int addr = ((2 * w + i) * 2 + (qd >> 1)) * 64 + m8 * 8 + (qd & 1) * 4;
                    uint2 u; u.x = pk2(v0, v1); u.y = pk2(v2, v3);
                    *(uint2*)(uT + addr) = u;
                }
            }
            __syncthreads();

            // ---- p2: ode^T = W2 u^T + b2 ; h += dt*ode (registers) ----
            f32x4 a2 = {0,0,0,0};
            #pragma unroll
            for (int kb = 0; kb < 8; ++kb) {
                const bf16x8 bf = *(const bf16x8*)(uT + kb * 256 + rbase);
                a2 = __builtin_amdgcn_mfma_f32_16x16x32_bf16(w2a[kb], bf, a2, 0, 0, 0);
            }
            #pragma unroll
            for (int r = 0; r < 4; ++r)
                hreg[r] = fmaf(dt, a2[r] + b2L[r], hreg[r]);
            if (valid) {
                uint2 u; u.x = pk2(hreg[0], hreg[1]); u.y = pk2(hreg[2], hreg[3]);
                *(uint2*)(hTpost + myAddr) = u;
            }
            __syncthreads();
            p3src = hTpost;
        } else {
            p3src = hTpre;
        }

        // ---- p3: gh^T = Whh h'^T + b_hh, then GRU fully in-register ----
        f32x4 a3[3] = {{0,0,0,0},{0,0,0,0},{0,0,0,0}};
        #pragma unroll
        for (int kb = 0; kb < 4; ++kb) {
            const bf16x8 bf = *(const bf16x8*)(p3src + kb * 256 + rbase);
            #pragma unroll
            for (int g = 0; g < 3; ++g)
                a3[g] = __builtin_amdgcn_mfma_f32_16x16x32_bf16(wha[g][kb], bf, a3[g], 0, 0, 0);
        }
        if (!(dt > 0.0f)) __syncthreads();   // dt==0: finish hTpre reads before overwrite

        {
            float hn[4];
            #pragma unroll
            for (int r = 0; r < 4; ++r) {
                const float rr = sigmoidf_(fmaf(x, wihL[0][r], bihL[0][r]) + a3[0][r] + bhL[0][r]);
                const float zz = sigmoidf_(fmaf(x, wihL[1][r], bihL[1][r]) + a3[1][r] + bhL[1][r]);
                const float nn = tanhf_(fmaf(rr, a3[2][r] + bhL[2][r],
                                             fmaf(x, wihL[2][r], bihL[2][r])));
                const float hv = hreg[r];
                const float hc = (1.0f - zz) * nn + zz * hv;
                hn[r] = mk * hc + (1.0f - mk) * hv;
                hreg[r] = hn[r];
            }
            if (valid) {
                uint2 u; u.x = pk2(hn[0], hn[1]); u.y = pk2(hn[2], hn[3]);
                *(uint2*)(hTpre + myAddr) = u;
            }
        }
        __syncthreads();
    }

    if (valid) {
        float4 o = make_float4(hreg[0], hreg[1], hreg[2], hreg[3]);
        *(float4*)(out + (size_t)(fbase + m8) * LAT + w * 16 + qd * 4) = o;
    }
}

extern "C" void kernel_launch(void* const* d_in, const int* in_sizes, int n_in,
                              void* d_out, int out_size, void* d_ws, size_t ws_size,
                              hipStream_t stream) {
    const float* times = (const float*)d_in[0];
    const float* vals  = (const float*)d_in[1];
    const float* mask  = (const float*)d_in[2];
    const float* W1    = (const float*)d_in[3];
    const float* b1    = (const float*)d_in[4];
    const float* W2    = (const float*)d_in[5];
    const float* b2    = (const float*)d_in[6];
    const float* W_ih  = (const float*)d_in[7];
    const float* b_ih  = (const float*)d_in[8];
    const float* Whh   = (const float*)d_in[9];
    const float* b_hh  = (const float*)d_in[10];
    float* out = (float*)d_out;

    odernn_kernel<<<NBLK, NTHR, 0, stream>>>(times, vals, mask,
                                             W1, b1, W2, b2,
                                             W_ih, b_ih, Whh, b_hh, out);
}

// Round 10
// 1236.336 us; speedup vs baseline: 2.4354x; 1.3438x over previous
//
#include <hip/hip_runtime.h>

#define T_STEPS 1024
#define FDIM    2048
#define LAT     128
#define HID     256
#define MB      8             // features per block
#define NTHR    512           // 8 waves, 2 per SIMD
#define NBLK    (FDIM / MB)   // 256 blocks = 1/CU

typedef __attribute__((ext_vector_type(8))) short bf16x8;
typedef __attribute__((ext_vector_type(4))) float f32x4;

// rcp instead of '/': -O3 w/o -ffast-math expands '/' into ~12-instr precise
// division. v_rcp_f32 ~1 ULP vs 2% threshold.
__device__ __forceinline__ float sigmoidf_(float x) {
    return __builtin_amdgcn_rcpf(1.0f + __expf(-x));
}
__device__ __forceinline__ float tanhf_(float x) {
    float ax = fabsf(x);
    float e  = __expf(-2.0f * ax);
    float t  = (1.0f - e) * __builtin_amdgcn_rcpf(1.0f + e);
    return copysignf(t, x);
}
__device__ __forceinline__ unsigned short f2bu(float x) {   // fp32->bf16 RNE bits
    unsigned u = __float_as_uint(x);
    u += 0x7fffu + ((u >> 16) & 1u);
    return (unsigned short)(u >> 16);
}
__device__ __forceinline__ short f2b(float x) { return (short)f2bu(x); }
__device__ __forceinline__ unsigned pk2(float a, float b) { // packed bf16x2 RNE
    return (unsigned)f2bu(a) | ((unsigned)f2bu(b) << 16);
}
// pick owned pair from a C-fragment: hf=0 -> (v0,v1), hf=1 -> (v2,v3).
// Lanes col 0..7 duplicate col 8..15 (identical B addresses), so splitting row
// ownership by col-bit3 halves the epilogue VALU with zero communication.
__device__ __forceinline__ float2 pick2(f32x4 v, int hf) {
    float a = hf ? v[2] : v[0];
    float b = hf ? v[3] : v[1];
    return make_float2(a, b);
}

// Activation^T LDS layout (B-operand): element (k, m) at short-offset
//   (k>>3)*64 + m*8 + (k&7)   [m in 0..7]
// B-frag read for lane (col,qd): 16B contiguous at (kb*4+qd)*64 + (col&7)*8;
// cols 8..15 duplicate cols 0..7 (same-address broadcast).

__global__ __launch_bounds__(NTHR, 2)
void odernn_kernel(const float* __restrict__ times,
                   const float* __restrict__ vals,
                   const float* __restrict__ mask,
                   const float* __restrict__ W1,  const float* __restrict__ b1,
                   const float* __restrict__ W2,  const float* __restrict__ b2,
                   const float* __restrict__ W_ih, const float* __restrict__ b_ih,
                   const float* __restrict__ Whh, const float* __restrict__ b_hh,
                   float* __restrict__ out)
{
    __shared__ float dts_s[T_STEPS];   // 4 KB
    __shared__ short hTpre[16 * 64];   // 2 KB  bf16 h^T (post-GRU)
    __shared__ short hTpost[16 * 64];  // 2 KB  bf16 h^T (post-ODE)
    __shared__ short uT[32 * 64];      // 4 KB  bf16 u^T

    const int tid = threadIdx.x;
    const int w   = tid >> 6;          // wave 0..7
    const int ln  = tid & 63;
    const int col = ln & 15;           // C/D col = feature (8..15 duplicate 0..7)
    const int qd  = ln >> 4;           // quad; C/D row = qd*4 + reg
    const int m8  = ln & 7;            // feature index
    const int hf  = (ln >> 3) & 1;     // row-half ownership: rows qd*4 + hf*2 + {0,1}
    const int fbase = blockIdx.x * MB;
    const int rbase = qd * 64 + m8 * 8;     // B-frag read offset (shorts)

    // ---------- prologue ----------
    for (int e = tid; e < T_STEPS; e += NTHR)
        dts_s[e] = (e == 0) ? 0.0f : (times[T_STEPS - e] - times[T_STEPS - 1 - e]);
    for (int e = tid; e < 16 * 64; e += NTHR) { hTpre[e] = 0; hTpost[e] = 0; }
    for (int e = tid; e < 32 * 64; e += NTHR) uT[e] = 0;

    // A-operand weight fragment: lane holds W[tb+col][kb*32 + qd*8 + j]
    auto loadW = [&](const float* __restrict__ W, int K, int tb, int kb) -> bf16x8 {
        const float* p = W + (size_t)(tb + col) * K + kb * 32 + qd * 8;
        const float4 a = *(const float4*)p;
        const float4 b = *(const float4*)(p + 4);
        bf16x8 r;
        r[0] = f2b(a.x); r[1] = f2b(a.y); r[2] = f2b(a.z); r[3] = f2b(a.w);
        r[4] = f2b(b.x); r[5] = f2b(b.y); r[6] = f2b(b.z); r[7] = f2b(b.w);
        return r;
    };

    // per-wave tiles (112 weight regs/lane, AGPR-resident):
    // p1: u-tiles {2w, 2w+1}; p2: ode-tile w; p3: gate tiles {w, 8+w, 16+w}
    bf16x8 w1a[2][4];
    #pragma unroll
    for (int i = 0; i < 2; ++i)
        #pragma unroll
        for (int kb = 0; kb < 4; ++kb) w1a[i][kb] = loadW(W1, LAT, (2 * w + i) * 16, kb);
    bf16x8 w2a[8];
    #pragma unroll
    for (int kb = 0; kb < 8; ++kb) w2a[kb] = loadW(W2, HID, w * 16, kb);
    bf16x8 wha[3][4];
    #pragma unroll
    for (int g = 0; g < 3; ++g)
        #pragma unroll
        for (int kb = 0; kb < 4; ++kb)
            wha[g][kb] = loadW(Whh, LAT, g * 128 + w * 16, kb);

    // per-lane constants for the OWNED rows: global row = base + qd*4 + hf*2 + j
    float b1L[2][2], b2L[2], bhL[3][2], wihL[3][2], bihL[3][2];
    #pragma unroll
    for (int i = 0; i < 2; ++i)
        #pragma unroll
        for (int j = 0; j < 2; ++j)
            b1L[i][j] = b1[(2 * w + i) * 16 + qd * 4 + hf * 2 + j];
    #pragma unroll
    for (int j = 0; j < 2; ++j) {
        const int c = w * 16 + qd * 4 + hf * 2 + j;
        b2L[j] = b2[c];
        #pragma unroll
        for (int g = 0; g < 3; ++g) {
            bhL[g][j]  = b_hh[g * 128 + c];
            wihL[g][j] = W_ih[g * 128 + c];
            bihL[g][j] = b_ih[g * 128 + c];
        }
    }
    float hreg[2] = {0.f, 0.f};   // fp32 master h: rows w*16+qd*4+hf*2+{0,1}, feature m8
    const int myAddr = (w * 2 + (qd >> 1)) * 64 + m8 * 8 + (qd & 1) * 4 + hf * 2;

    __syncthreads();

    for (int t = 0; t < T_STEPS; ++t) {
        const float dt = dts_s[t];
        const size_t rowoff = (size_t)(T_STEPS - 1 - t) * FDIM + fbase;
        const float x  = vals[rowoff + m8];       // prefetch; used in p3 epilogue
        const float mk = mask[rowoff + m8];
        const short* p3src;

        if (dt > 0.0f) {
            // ---- p1: u^T = tanh(W1 h^T + b1), 2 tiles ----
            f32x4 a1[2] = {{0,0,0,0},{0,0,0,0}};
            #pragma unroll
            for (int kb = 0; kb < 4; ++kb) {
                const bf16x8 bf = *(const bf16x8*)(hTpre + kb * 256 + rbase);
                #pragma unroll
                for (int i = 0; i < 2; ++i)
                    a1[i] = __builtin_amdgcn_mfma_f32_16x16x32_bf16(w1a[i][kb], bf, a1[i], 0, 0, 0);
            }
            #pragma unroll
            for (int i = 0; i < 2; ++i) {
                const float2 p = pick2(a1[i], hf);
                const float v0 = tanhf_(p.x + b1L[i][0]);
                const float v1 = tanhf_(p.y + b1L[i][1]);
                const int addr = ((2 * w + i) * 2 + (qd >> 1)) * 64 + m8 * 8 + (qd & 1) * 4 + hf * 2;
                *(unsigned*)(uT + addr) = pk2(v0, v1);
            }
            __syncthreads();

            // ---- p2: ode^T = W2 u^T + b2 ; h += dt*ode (registers) ----
            f32x4 a2 = {0,0,0,0};
            #pragma unroll
            for (int kb = 0; kb < 8; ++kb) {
                const bf16x8 bf = *(const bf16x8*)(uT + kb * 256 + rbase);
                a2 = __builtin_amdgcn_mfma_f32_16x16x32_bf16(w2a[kb], bf, a2, 0, 0, 0);
            }
            {
                const float2 p = pick2(a2, hf);
                hreg[0] = fmaf(dt, p.x + b2L[0], hreg[0]);
                hreg[1] = fmaf(dt, p.y + b2L[1], hreg[1]);
                *(unsigned*)(hTpost + myAddr) = pk2(hreg[0], hreg[1]);
            }
            __syncthreads();
            p3src = hTpost;
        } else {
            p3src = hTpre;
        }

        // ---- p3: gh^T = Whh h'^T + b_hh, then GRU fully in-register ----
        f32x4 a3[3] = {{0,0,0,0},{0,0,0,0},{0,0,0,0}};
        #pragma unroll
        for (int kb = 0; kb < 4; ++kb) {
            const bf16x8 bf = *(const bf16x8*)(p3src + kb * 256 + rbase);
            #pragma unroll
            for (int g = 0; g < 3; ++g)
                a3[g] = __builtin_amdgcn_mfma_f32_16x16x32_bf16(wha[g][kb], bf, a3[g], 0, 0, 0);
        }
        if (!(dt > 0.0f)) __syncthreads();   // dt==0: finish hTpre reads before overwrite

        {
            const float2 gR = pick2(a3[0], hf);
            const float2 gZ = pick2(a3[1], hf);
            const float2 gN = pick2(a3[2], hf);
            const float gRv[2] = {gR.x, gR.y}, gZv[2] = {gZ.x, gZ.y}, gNv[2] = {gN.x, gN.y};
            #pragma unroll
            for (int j = 0; j < 2; ++j) {
                const float rr = sigmoidf_(fmaf(x, wihL[0][j], bihL[0][j]) + gRv[j] + bhL[0][j]);
                const float zz = sigmoidf_(fmaf(x, wihL[1][j], bihL[1][j]) + gZv[j] + bhL[1][j]);
                const float nn = tanhf_(fmaf(rr, gNv[j] + bhL[2][j],
                                             fmaf(x, wihL[2][j], bihL[2][j])));
                const float hv = hreg[j];
                const float hc = (1.0f - zz) * nn + zz * hv;
                hreg[j] = mk * hc + (1.0f - mk) * hv;
            }
            *(unsigned*)(hTpre + myAddr) = pk2(hreg[0], hreg[1]);
        }
        __syncthreads();
    }

    {
        float2 o = make_float2(hreg[0], hreg[1]);
        *(float2*)(out + (size_t)(fbase + m8) * LAT + w * 16 + qd * 4 + hf * 2) = o;
    }
}

extern "C" void kernel_launch(void* const* d_in, const int* in_sizes, int n_in,
                              void* d_out, int out_size, void* d_ws, size_t ws_size,
                              hipStream_t stream) {
    const float* times = (const float*)d_in[0];
    const float* vals  = (const float*)d_in[1];
    const float* mask  = (const float*)d_in[2];
    const float* W1    = (const float*)d_in[3];
    const float* b1    = (const float*)d_in[4];
    const float* W2    = (const float*)d_in[5];
    const float* b2    = (const float*)d_in[6];
    const float* W_ih  = (const float*)d_in[7];
    const float* b_ih  = (const float*)d_in[8];
    const float* Whh   = (const float*)d_in[9];
    const float* b_hh  = (const float*)d_in[10];
    float* out = (float*)d_out;

    odernn_kernel<<<NBLK, NTHR, 0, stream>>>(times, vals, mask,
                                             W1, b1, W2, b2,
                                             W_ih, b_ih, Whh, b_hh, out);
}

// Round 11
// 1124.298 us; speedup vs baseline: 2.6781x; 1.0997x over previous
//
#include <hip/hip_runtime.h>

#define T_STEPS 1024
#define FDIM    2048
#define LAT     128
#define HID     256
#define MB      8             // features per block
#define NTHR    512           // 8 waves, 2 per SIMD
#define NBLK    (FDIM / MB)   // 256 blocks = 1/CU

typedef __attribute__((ext_vector_type(8))) short bf16x8;
typedef __attribute__((ext_vector_type(4))) float f32x4;

#define L2E  1.4426950408889634f   // log2(e)
#define C2E  2.8853900817779268f   // 2*log2(e)

__device__ __forceinline__ float exp2_(float x) {
#if __has_builtin(__builtin_amdgcn_exp2f)
    return __builtin_amdgcn_exp2f(x);
#else
    return __expf(0.6931471805599453f * x);
#endif
}
__device__ __forceinline__ float rcp_(float x) { return __builtin_amdgcn_rcpf(x); }
// tanh(y) = 1 - 2/(1+2^(C2E*y)): inf-safe (y->+inf: 2^big=inf, rcp=0, ->1;
// y->-inf: 2^small=0, rcp(1)=1, ->-1). 5 instr with bias folded into exp2 domain.

__device__ __forceinline__ unsigned short f2bu(float x) {   // fp32->bf16 RNE bits
    unsigned u = __float_as_uint(x);
    u += 0x7fffu + ((u >> 16) & 1u);
    return (unsigned short)(u >> 16);
}
__device__ __forceinline__ short f2b(float x) { return (short)f2bu(x); }
__device__ __forceinline__ unsigned pk2(float a, float b) { // packed bf16x2 RNE
    return (unsigned)f2bu(a) | ((unsigned)f2bu(b) << 16);
}
// pick owned row-pair from a C-fragment: hf=0 -> (v0,v1), hf=1 -> (v2,v3)
__device__ __forceinline__ float2 pick2(f32x4 v, int hf) {
    float a = hf ? v[2] : v[0];
    float b = hf ? v[3] : v[1];
    return make_float2(a, b);
}

// Activation^T LDS layout (B-operand): element (k, m) at short-offset
//   (k>>3)*64 + m*8 + (k&7)   [m in 0..7]
// B-frag read for lane (col,qd): 16B contiguous at (kb*4+qd)*64 + (col&7)*8;
// cols 8..15 duplicate cols 0..7 (same-address broadcast).

__global__ __launch_bounds__(NTHR, 2)
void odernn_kernel(const float* __restrict__ times,
                   const float* __restrict__ vals,
                   const float* __restrict__ mask,
                   const float* __restrict__ W1,  const float* __restrict__ b1,
                   const float* __restrict__ W2,  const float* __restrict__ b2,
                   const float* __restrict__ W_ih, const float* __restrict__ b_ih,
                   const float* __restrict__ Whh, const float* __restrict__ b_hh,
                   float* __restrict__ out)
{
    __shared__ float dts_s[T_STEPS];   // 4 KB
    __shared__ short hTpre[16 * 64];   // 2 KB  bf16 h^T (post-GRU)
    __shared__ short hTpost[16 * 64];  // 2 KB  bf16 h^T (post-ODE)
    __shared__ short uT[32 * 64];      // 4 KB  bf16 u^T

    const int tid = threadIdx.x;
    const int w   = tid >> 6;          // wave 0..7
    const int ln  = tid & 63;
    const int col = ln & 15;           // C/D col = feature (8..15 duplicate 0..7)
    const int qd  = ln >> 4;           // quad; C/D row = qd*4 + reg
    const int m8  = ln & 7;            // feature index
    const int hf  = (ln >> 3) & 1;     // row-half ownership: rows qd*4 + hf*2 + {0,1}
    const int fbase = blockIdx.x * MB;
    const int rbase = qd * 64 + m8 * 8;     // B-frag read offset (shorts)

    // ---------- prologue ----------
    for (int e = tid; e < T_STEPS; e += NTHR)
        dts_s[e] = (e == 0) ? 0.0f : (times[T_STEPS - e] - times[T_STEPS - 1 - e]);
    for (int e = tid; e < 16 * 64; e += NTHR) { hTpre[e] = 0; hTpost[e] = 0; }

    // A-operand weight fragment: lane holds W[tb+col][kb*32 + qd*8 + j]
    auto loadW = [&](const float* __restrict__ W, int K, int tb, int kb) -> bf16x8 {
        const float* p = W + (size_t)(tb + col) * K + kb * 32 + qd * 8;
        const float4 a = *(const float4*)p;
        const float4 b = *(const float4*)(p + 4);
        bf16x8 r;
        r[0] = f2b(a.x); r[1] = f2b(a.y); r[2] = f2b(a.z); r[3] = f2b(a.w);
        r[4] = f2b(b.x); r[5] = f2b(b.y); r[6] = f2b(b.z); r[7] = f2b(b.w);
        return r;
    };

    // per-wave tiles (112 weight regs/lane, AGPR-resident):
    // p1: u-tiles {2w, 2w+1}; p2: ode-tile w; p3: gate tiles {w, 8+w, 16+w}
    bf16x8 w1a[2][4];
    #pragma unroll
    for (int i = 0; i < 2; ++i)
        #pragma unroll
        for (int kb = 0; kb < 4; ++kb) w1a[i][kb] = loadW(W1, LAT, (2 * w + i) * 16, kb);
    bf16x8 w2a[8];
    #pragma unroll
    for (int kb = 0; kb < 8; ++kb) w2a[kb] = loadW(W2, HID, w * 16, kb);
    bf16x8 wha[3][4];
    #pragma unroll
    for (int g = 0; g < 3; ++g)
        #pragma unroll
        for (int kb = 0; kb < 4; ++kb)
            wha[g][kb] = loadW(Whh, LAT, g * 128 + w * 16, kb);

    // per-lane constants for OWNED rows c = w*16 + qd*4 + hf*2 + j,
    // pre-scaled into the exp2 domain so each activation is minimal-instr:
    //  p1 tanh:  arg2 = fmaf(a1, C2E, cb1)                  (cb1 = C2E*b1)
    //  r/z sig:  arg2 = fmaf(a3, -L2E, fmaf(x, wS, bS))     (wS=-L2E*wih, bS=-L2E*(bih+bhh))
    //  n  tanh:  arg2 = fmaf(r, fmaf(a3n, C2E, bhnC), fmaf(x, wnC, bnC))
    float cb1L[2][2], b2L[2];
    float wrS[2], brS[2], wzS[2], bzS[2], wnC[2], bnC[2], bhnC[2];
    #pragma unroll
    for (int i = 0; i < 2; ++i)
        #pragma unroll
        for (int j = 0; j < 2; ++j)
            cb1L[i][j] = C2E * b1[(2 * w + i) * 16 + qd * 4 + hf * 2 + j];
    #pragma unroll
    for (int j = 0; j < 2; ++j) {
        const int c = w * 16 + qd * 4 + hf * 2 + j;
        b2L[j]  = b2[c];
        wrS[j]  = -L2E * W_ih[c];
        brS[j]  = -L2E * (b_ih[c] + b_hh[c]);
        wzS[j]  = -L2E * W_ih[128 + c];
        bzS[j]  = -L2E * (b_ih[128 + c] + b_hh[128 + c]);
        wnC[j]  =  C2E * W_ih[256 + c];
        bnC[j]  =  C2E * b_ih[256 + c];
        bhnC[j] =  C2E * b_hh[256 + c];
    }
    float hreg[2] = {0.f, 0.f};   // fp32 master h: rows w*16+qd*4+hf*2+{0,1}, feature m8
    const int myAddr = (w * 2 + (qd >> 1)) * 64 + m8 * 8 + (qd & 1) * 4 + hf * 2;

    // decrementing observation pointers (row T-1-t, own feature)
    const float* vp = vals + (size_t)(T_STEPS - 1) * FDIM + fbase + m8;
    const float* mp = mask + (size_t)(T_STEPS - 1) * FDIM + fbase + m8;

    __syncthreads();

    // Branch-free loop: dt==0 gives h' = fmaf(0, ode, h) == h bit-exactly, so
    // the reference's where(dt>0) needs no control flow (ties ~never anyway).
    for (int t = 0; t < T_STEPS; ++t) {
        const float dt = dts_s[t];
        const float x  = *vp;  vp -= FDIM;
        const float mk = *mp;  mp -= FDIM;

        // ---- p1: u^T = tanh(W1 h^T + b1), 2 tiles ----
        f32x4 a1[2] = {{0,0,0,0},{0,0,0,0}};
        #pragma unroll
        for (int kb = 0; kb < 4; ++kb) {
            const bf16x8 bf = *(const bf16x8*)(hTpre + kb * 256 + rbase);
            #pragma unroll
            for (int i = 0; i < 2; ++i)
                a1[i] = __builtin_amdgcn_mfma_f32_16x16x32_bf16(w1a[i][kb], bf, a1[i], 0, 0, 0);
        }
        #pragma unroll
        for (int i = 0; i < 2; ++i) {
            const float2 p = pick2(a1[i], hf);
            const float v0 = fmaf(-2.f, rcp_(1.f + exp2_(fmaf(p.x, C2E, cb1L[i][0]))), 1.f);
            const float v1 = fmaf(-2.f, rcp_(1.f + exp2_(fmaf(p.y, C2E, cb1L[i][1]))), 1.f);
            const int addr = ((2 * w + i) * 2 + (qd >> 1)) * 64 + m8 * 8 + (qd & 1) * 4 + hf * 2;
            *(unsigned*)(uT + addr) = pk2(v0, v1);
        }
        __syncthreads();

        // ---- p2: ode^T = W2 u^T + b2 ; h += dt*ode. Dual accumulators to
        // halve the serial MFMA dependency chain (8 -> 4+4). ----
        f32x4 a2a = {0,0,0,0}, a2b = {0,0,0,0};
        #pragma unroll
        for (int kb = 0; kb < 4; ++kb) {
            const bf16x8 bfa = *(const bf16x8*)(uT + kb * 256 + rbase);
            const bf16x8 bfb = *(const bf16x8*)(uT + (kb + 4) * 256 + rbase);
            a2a = __builtin_amdgcn_mfma_f32_16x16x32_bf16(w2a[kb],     bfa, a2a, 0, 0, 0);
            a2b = __builtin_amdgcn_mfma_f32_16x16x32_bf16(w2a[kb + 4], bfb, a2b, 0, 0, 0);
        }
        {
            const f32x4 a2 = a2a + a2b;
            const float2 p = pick2(a2, hf);
            hreg[0] = fmaf(dt, p.x + b2L[0], hreg[0]);
            hreg[1] = fmaf(dt, p.y + b2L[1], hreg[1]);
            *(unsigned*)(hTpost + myAddr) = pk2(hreg[0], hreg[1]);
        }
        __syncthreads();

        // ---- p3: gh^T = Whh h'^T (+ biases folded), GRU fully in-register ----
        f32x4 a3[3] = {{0,0,0,0},{0,0,0,0},{0,0,0,0}};
        #pragma unroll
        for (int kb = 0; kb < 4; ++kb) {
            const bf16x8 bf = *(const bf16x8*)(hTpost + kb * 256 + rbase);
            #pragma unroll
            for (int g = 0; g < 3; ++g)
                a3[g] = __builtin_amdgcn_mfma_f32_16x16x32_bf16(wha[g][kb], bf, a3[g], 0, 0, 0);
        }
        {
            const float2 gR = pick2(a3[0], hf);
            const float2 gZ = pick2(a3[1], hf);
            const float2 gN = pick2(a3[2], hf);
            const float gRv[2] = {gR.x, gR.y}, gZv[2] = {gZ.x, gZ.y}, gNv[2] = {gN.x, gN.y};
            #pragma unroll
            for (int j = 0; j < 2; ++j) {
                const float sr = rcp_(1.f + exp2_(fmaf(gRv[j], -L2E, fmaf(x, wrS[j], brS[j]))));
                const float sz = rcp_(1.f + exp2_(fmaf(gZv[j], -L2E, fmaf(x, wzS[j], bzS[j]))));
                const float yn = fmaf(sr, fmaf(gNv[j], C2E, bhnC[j]), fmaf(x, wnC[j], bnC[j]));
                const float nn = fmaf(-2.f, rcp_(1.f + exp2_(yn)), 1.f);
                const float hv = hreg[j];
                const float hc = fmaf(sz, hv - nn, nn);          // (1-z)n + z*h
                hreg[j] = fmaf(mk, hc - hv, hv);                 // mask blend
            }
            *(unsigned*)(hTpre + myAddr) = pk2(hreg[0], hreg[1]);
        }
        __syncthreads();
    }

    {
        float2 o = make_float2(hreg[0], hreg[1]);
        *(float2*)(out + (size_t)(fbase + m8) * LAT + w * 16 + qd * 4 + hf * 2) = o;
    }
}

extern "C" void kernel_launch(void* const* d_in, const int* in_sizes, int n_in,
                              void* d_out, int out_size, void* d_ws, size_t ws_size,
                              hipStream_t stream) {
    const float* times = (const float*)d_in[0];
    const float* vals  = (const float*)d_in[1];
    const float* mask  = (const float*)d_in[2];
    const float* W1    = (const float*)d_in[3];
    const float* b1    = (const float*)d_in[4];
    const float* W2    = (const float*)d_in[5];
    const float* b2    = (const float*)d_in[6];
    const float* W_ih  = (const float*)d_in[7];
    const float* b_ih  = (const float*)d_in[8];
    const float* Whh   = (const float*)d_in[9];
    const float* b_hh  = (const float*)d_in[10];
    float* out = (float*)d_out;

    odernn_kernel<<<NBLK, NTHR, 0, stream>>>(times, vals, mask,
                                             W1, b1, W2, b2,
                                             W_ih, b_ih, Whh, b_hh, out);
}